// Round 1
// baseline (513.930 us; speedup 1.0000x reference)
//
#include <hip/hip_runtime.h>
#include <stdint.h>

#define B_ 256
#define N_ 256
#define F_ 64
#define H_ 512

typedef _Float16 f16;
typedef _Float16 f16x8 __attribute__((ext_vector_type(8)));
typedef _Float16 f16x4 __attribute__((ext_vector_type(4)));
typedef float    f32x4 __attribute__((ext_vector_type(4)));

__device__ __forceinline__ float sigmoidf_(float x) {
    return 1.0f / (1.0f + __expf(-x));
}

// ---------------------------------------------------------------------------
// k_sig: S[b,i,j] = sigmoid(z[b,i,j]) (f16), R[b,i] = row sums (fp32)
// grid (N_, B_) x 256
__global__ __launch_bounds__(256) void k_sig(const float* __restrict__ z,
                                             f16* __restrict__ S,
                                             float* __restrict__ R) {
    int b = blockIdx.y, i = blockIdx.x, j = threadIdx.x;
    size_t base = ((size_t)(b * N_ + i)) * N_;
    float s = sigmoidf_(z[base + j]);
    S[base + j] = (f16)s;
    for (int off = 32; off; off >>= 1) s += __shfl_down(s, off, 64);
    __shared__ float ws4[4];
    int lane = j & 63, w = j >> 6;
    if (lane == 0) ws4[w] = s;
    __syncthreads();
    if (j == 0) R[b * N_ + i] = ws4[0] + ws4[1] + ws4[2] + ws4[3];
}

// ---------------------------------------------------------------------------
// k_col: colsum C[b,j], then Dinv[b,j] = rsqrt(1 + 1e-6 + 0.5*(R+C))
// grid B_ x 256
__global__ __launch_bounds__(256) void k_col(const f16* __restrict__ S,
                                             const float* __restrict__ R,
                                             float* __restrict__ Dinv) {
    int b = blockIdx.x, j = threadIdx.x;
    const f16* Sb = S + (size_t)b * N_ * N_;
    float c = 0.f;
    for (int i = 0; i < N_; i++) c += (float)Sb[i * N_ + j];
    float D = 1.0f + 1e-6f + 0.5f * (R[b * N_ + j] + c);
    Dinv[b * N_ + j] = rsqrtf(D);
}

// ---------------------------------------------------------------------------
// k_norma: nA[b,i,j] = (0.5*(S[i,j]+S[j,i]) + (i==j)) * Dinv[i]*Dinv[j]  (f16)
// grid (N_, B_) x 256
__global__ __launch_bounds__(256) void k_norma(const f16* __restrict__ S,
                                               const float* __restrict__ Dinv,
                                               f16* __restrict__ nA) {
    int b = blockIdx.y, i = blockIdx.x, j = threadIdx.x;
    const f16* Sb = S + (size_t)b * N_ * N_;
    float v = 0.5f * ((float)Sb[i * N_ + j] + (float)Sb[j * N_ + i]);
    if (i == j) v += 1.0f;
    v *= Dinv[b * N_ + i] * Dinv[b * N_ + j];
    nA[(size_t)b * N_ * N_ + (size_t)i * N_ + j] = (f16)v;
}

// ---------------------------------------------------------------------------
// k_xw1: XW1t[h, node] = sum_k ne[node,k]*w1[k,h] + b1[h]   (f16, transposed)
// grid H_ x 256 (thread = node)
__global__ __launch_bounds__(256) void k_xw1(const float* __restrict__ ne,
                                             const float* __restrict__ w1,
                                             const float* __restrict__ b1,
                                             f16* __restrict__ XW1t) {
    int h = blockIdx.x;
    int node = threadIdx.x;
    float s = b1[h];
    #pragma unroll 8
    for (int k = 0; k < F_; k++) s += ne[node * F_ + k] * w1[k * H_ + h];
    XW1t[h * N_ + node] = (f16)s;
}

// ---------------------------------------------------------------------------
// k_wt: w{2,3}t[n,k] = w{2,3}[k,n]   (f16 transpose)
// grid (1024, 2) x 256
__global__ __launch_bounds__(256) void k_wt(const float* __restrict__ w2,
                                            const float* __restrict__ w3,
                                            f16* __restrict__ w2t,
                                            f16* __restrict__ w3t) {
    int which = blockIdx.y;
    const float* src = which ? w3 : w2;
    f16* dst = which ? w3t : w2t;
    int idx = blockIdx.x * 256 + threadIdx.x;   // 0..262143
    int k = idx >> 9, n = idx & 511;
    dst[n * H_ + k] = (f16)src[k * H_ + n];
}

// ---------------------------------------------------------------------------
// k_gemm: C(128x128 tile) = A(rows m, K) @ Bt(rows n, K)^T
// MODE 0: Out[b][node][512] = relu(acc)          (GCN aggregation)
// MODE 1: Out[b][n][256]    = acc + bias[n]      (feature transform, transposed out)
// grid (8, B_) x 256: blockIdx.x&1 -> m-tile, >>1 -> n-tile
template <int KDIM, int MODE>
__global__ __launch_bounds__(256) void k_gemm(const f16* __restrict__ A, long aBatch,
                                              const f16* __restrict__ Bt, long bBatch,
                                              f16* __restrict__ Out,
                                              const float* __restrict__ bias) {
    __shared__ f16 As[128 * 32];
    __shared__ f16 Bs[128 * 32];
    const int tid  = threadIdx.x;
    const int lane = tid & 63, wave = tid >> 6;
    const int wm = wave >> 1, wn = wave & 1;
    const int b  = blockIdx.y;
    const int m0 = (blockIdx.x & 1) * 128;
    const int n0 = (blockIdx.x >> 1) * 128;

    const f16* Ab = A + (size_t)b * aBatch;
    const f16* Bb = Bt + (size_t)b * bBatch;

    f32x4 acc[4][4];
    #pragma unroll
    for (int i = 0; i < 4; i++)
        #pragma unroll
        for (int j = 0; j < 4; j++)
            #pragma unroll
            for (int r = 0; r < 4; r++) acc[i][j][r] = 0.0f;

    const int srow = (lane >> 2);        // 0..15 within chunk
    const int scol = (lane & 3) * 8;     // halves

    for (int kk = 0; kk < KDIM; kk += 32) {
        #pragma unroll
        for (int c = 0; c < 2; c++) {
            int chunk = wave * 2 + c;            // 0..7
            int row = chunk * 16 + srow;         // 0..127
            __builtin_amdgcn_global_load_lds(
                (__attribute__((address_space(1))) void*)(Ab + (size_t)(m0 + row) * KDIM + kk + scol),
                (__attribute__((address_space(3))) void*)(&As[chunk * 512]), 16, 0, 0);
            __builtin_amdgcn_global_load_lds(
                (__attribute__((address_space(1))) void*)(Bb + (size_t)(n0 + row) * KDIM + kk + scol),
                (__attribute__((address_space(3))) void*)(&Bs[chunk * 512]), 16, 0, 0);
        }
        __syncthreads();

        f16x8 aF[4], bF[4];
        #pragma unroll
        for (int t = 0; t < 4; t++) {
            aF[t] = *(const f16x8*)&As[(wm * 64 + t * 16 + (lane & 15)) * 32 + (lane >> 4) * 8];
            bF[t] = *(const f16x8*)&Bs[(wn * 64 + t * 16 + (lane & 15)) * 32 + (lane >> 4) * 8];
        }
        #pragma unroll
        for (int mt = 0; mt < 4; mt++)
            #pragma unroll
            for (int nt = 0; nt < 4; nt++)
                acc[mt][nt] = __builtin_amdgcn_mfma_f32_16x16x32_f16(aF[mt], bF[nt], acc[mt][nt], 0, 0, 0);
        __syncthreads();
    }

    const int quad = lane >> 4, ln15 = lane & 15;
    if (MODE == 0) {
        f16* Ob = Out + (size_t)b * (N_ * H_);
        #pragma unroll
        for (int mt = 0; mt < 4; mt++) {
            int node = m0 + wm * 64 + mt * 16 + quad * 4;
            #pragma unroll
            for (int nt = 0; nt < 4; nt++) {
                int h = n0 + wn * 64 + nt * 16 + ln15;
                #pragma unroll
                for (int rr = 0; rr < 4; rr++) {
                    float v = acc[mt][nt][rr];
                    v = v > 0.f ? v : 0.f;
                    Ob[(size_t)(node + rr) * H_ + h] = (f16)v;
                }
            }
        }
    } else {
        f16* Ob = Out + (size_t)b * (H_ * N_);
        #pragma unroll
        for (int nt = 0; nt < 4; nt++) {
            int n = n0 + wn * 64 + nt * 16 + ln15;
            float bv = bias[n];
            #pragma unroll
            for (int mt = 0; mt < 4; mt++) {
                int node = m0 + wm * 64 + mt * 16 + quad * 4;
                f16x4 v;
                #pragma unroll
                for (int rr = 0; rr < 4; rr++) v[rr] = (f16)(acc[mt][nt][rr] + bv);
                *(f16x4*)&Ob[(size_t)n * N_ + node] = v;
            }
        }
    }
}

// ---------------------------------------------------------------------------
// k_out: graph_emb = mean_nodes(H3), logits = g @ fcw + fcb
// grid B_ x 256
__global__ __launch_bounds__(256) void k_out(const f16* __restrict__ H3,
                                             const float* __restrict__ fcw,
                                             const float* __restrict__ fcb,
                                             float* __restrict__ out) {
    int b = blockIdx.x, tid = threadIdx.x;
    __shared__ float g[H_];
    const f16* Hb = H3 + (size_t)b * (N_ * H_);
    for (int h = tid; h < H_; h += 256) {
        float s = 0.f;
        for (int node = 0; node < N_; node++) s += (float)Hb[node * H_ + h];
        g[h] = s * (1.0f / N_);
    }
    __syncthreads();
    float p0 = 0.f, p1 = 0.f;
    for (int h = tid; h < H_; h += 256) {
        p0 += g[h] * fcw[h * 2 + 0];
        p1 += g[h] * fcw[h * 2 + 1];
    }
    for (int off = 32; off; off >>= 1) {
        p0 += __shfl_down(p0, off, 64);
        p1 += __shfl_down(p1, off, 64);
    }
    __shared__ float r0[4], r1[4];
    int lane = tid & 63, w = tid >> 6;
    if (lane == 0) { r0[w] = p0; r1[w] = p1; }
    __syncthreads();
    if (tid == 0) out[b * 2 + 0] = r0[0] + r0[1] + r0[2] + r0[3] + fcb[0];
    if (tid == 1) out[b * 2 + 1] = r1[0] + r1[1] + r1[2] + r1[3] + fcb[1];
}

// ---------------------------------------------------------------------------
extern "C" void kernel_launch(void* const* d_in, const int* in_sizes, int n_in,
                              void* d_out, int out_size, void* d_ws, size_t ws_size,
                              hipStream_t stream) {
    const float* z   = (const float*)d_in[0];
    const float* ne  = (const float*)d_in[1];
    const float* w1  = (const float*)d_in[2];
    const float* b1  = (const float*)d_in[3];
    const float* w2  = (const float*)d_in[4];
    const float* b2  = (const float*)d_in[5];
    const float* w3  = (const float*)d_in[6];
    const float* b3  = (const float*)d_in[7];
    const float* fcw = (const float*)d_in[8];
    const float* fcb = (const float*)d_in[9];
    float* out = (float*)d_out;

    char* ws = (char*)d_ws;
    // Layout (bytes). S aliases T: S dead before first write to T.
    f16*   T    = (f16*)(ws + 0);            // B*512*256 f16 = 67,108,864
    f16*   S    = (f16*)(ws + 0);            // B*256*256 f16 = 33,554,432 (alias)
    f16*   nA   = (f16*)(ws + 67108864);     // 33,554,432
    f16*   Hh   = (f16*)(ws + 100663296);    // B*256*512 f16 = 67,108,864
    f16*   XW1t = (f16*)(ws + 167772160);    //    262,144
    f16*   w2t  = (f16*)(ws + 168034304);    //    524,288
    f16*   w3t  = (f16*)(ws + 168558592);    //    524,288
    float* R    = (float*)(ws + 169082880);  //    262,144
    float* Dinv = (float*)(ws + 169345024);  //    262,144  (total ~161.7 MB)

    // adjacency preprocessing
    k_sig  <<<dim3(N_, B_), 256, 0, stream>>>(z, S, R);
    k_col  <<<B_,           256, 0, stream>>>(S, R, Dinv);
    k_norma<<<dim3(N_, B_), 256, 0, stream>>>(S, Dinv, nA);
    // weight preprocessing
    k_xw1  <<<H_,             256, 0, stream>>>(ne, w1, b1, XW1t);
    k_wt   <<<dim3(1024, 2),  256, 0, stream>>>(w2, w3, w2t, w3t);

    // Layer 1: H = relu(nA @ XW1)      (XW1t shared: bBatch = 0)
    k_gemm<256, 0><<<dim3(8, B_), 256, 0, stream>>>(nA, 65536, XW1t, 0, Hh, nullptr);
    // T2 = H @ w2 + b2  (transposed out)
    k_gemm<512, 1><<<dim3(8, B_), 256, 0, stream>>>(Hh, 131072, w2t, 0, T, b2);
    // Layer 2: H = relu(nA @ T2)
    k_gemm<256, 0><<<dim3(8, B_), 256, 0, stream>>>(nA, 65536, T, 131072, Hh, nullptr);
    // T3 = H @ w3 + b3
    k_gemm<512, 1><<<dim3(8, B_), 256, 0, stream>>>(Hh, 131072, w3t, 0, T, b3);
    // Layer 3: H = relu(nA @ T3)
    k_gemm<256, 0><<<dim3(8, B_), 256, 0, stream>>>(nA, 65536, T, 131072, Hh, nullptr);

    // readout
    k_out<<<B_, 256, 0, stream>>>(Hh, fcw, fcb, out);
}

// Round 2
// 419.740 us; speedup vs baseline: 1.2244x; 1.2244x over previous
//
#include <hip/hip_runtime.h>
#include <stdint.h>

#define B_ 256
#define N_ 256
#define F_ 64
#define H_ 512

typedef _Float16 f16;
typedef _Float16 f16x8 __attribute__((ext_vector_type(8)));
typedef _Float16 f16x4 __attribute__((ext_vector_type(4)));
typedef float    f32x4 __attribute__((ext_vector_type(4)));

__device__ __forceinline__ float sigmoidf_(float x) {
    return 1.0f / (1.0f + __expf(-x));
}

// ---------------------------------------------------------------------------
// k_sums: one pass over z. R[b,i] = row sums of sigmoid(z). Cg[b,j] += col
// partials (atomic, Cg pre-zeroed). grid (4 row-chunks, B_) x 256.
__global__ __launch_bounds__(256) void k_sums(const float* __restrict__ z,
                                              float* __restrict__ R,
                                              float* __restrict__ Cg) {
    int b = blockIdx.y, c = blockIdx.x;
    int tid = threadIdx.x, lane = tid & 63, w = tid >> 6;
    float colacc[4] = {0.f, 0.f, 0.f, 0.f};
    for (int r = 0; r < 16; r++) {
        int i = c * 64 + w * 16 + r;
        float4 v = *(const float4*)(z + ((size_t)(b * N_ + i)) * N_ + lane * 4);
        float s0 = sigmoidf_(v.x), s1 = sigmoidf_(v.y),
              s2 = sigmoidf_(v.z), s3 = sigmoidf_(v.w);
        colacc[0] += s0; colacc[1] += s1; colacc[2] += s2; colacc[3] += s3;
        float rs = s0 + s1 + s2 + s3;
        for (int off = 32; off; off >>= 1) rs += __shfl_down(rs, off, 64);
        if (lane == 0) R[b * N_ + i] = rs;
    }
    __shared__ float cbuf[4][N_];
    #pragma unroll
    for (int k = 0; k < 4; k++) cbuf[w][lane * 4 + k] = colacc[k];
    __syncthreads();
    float s = cbuf[0][tid] + cbuf[1][tid] + cbuf[2][tid] + cbuf[3][tid];
    atomicAdd(Cg + b * N_ + tid, s);
}

// ---------------------------------------------------------------------------
// k_norma2: nA[b,i,j] = (0.5*(sig z_ij + sig z_ji) + delta_ij)*Di*Dj  (f16)
// Tiled 128x128; mirror tile staged through LDS (row-major load, transposed
// read, stride 129 f16 so transposed lanes spread across banks).
// grid (4 tiles, B_) x 256.
__global__ __launch_bounds__(256) void k_norma2(const float* __restrict__ z,
                                                const float* __restrict__ R,
                                                const float* __restrict__ Cg,
                                                f16* __restrict__ nA) {
    __shared__ f16 mir[128 * 129];
    __shared__ float Di[128], Dj[128];
    int b = blockIdx.y, tile = blockIdx.x;
    int i0 = (tile >> 1) * 128, j0 = (tile & 1) * 128;
    int tid = threadIdx.x;

    // stage mirror tile (rows j, cols i) with sigmoid applied
    #pragma unroll
    for (int it = 0; it < 16; it++) {
        int u = it * 256 + tid;
        int jl = u >> 5, c4 = (u & 31) * 4;
        float4 v = *(const float4*)(z + ((size_t)(b * N_ + j0 + jl)) * N_ + i0 + c4);
        mir[jl * 129 + c4 + 0] = (f16)sigmoidf_(v.x);
        mir[jl * 129 + c4 + 1] = (f16)sigmoidf_(v.y);
        mir[jl * 129 + c4 + 2] = (f16)sigmoidf_(v.z);
        mir[jl * 129 + c4 + 3] = (f16)sigmoidf_(v.w);
    }
    if (tid < 128) {
        Di[tid] = rsqrtf(1.0f + 1e-6f + 0.5f * (R[b * N_ + i0 + tid] + Cg[b * N_ + i0 + tid]));
    } else {
        int jl = tid - 128;
        Dj[jl] = rsqrtf(1.0f + 1e-6f + 0.5f * (R[b * N_ + j0 + jl] + Cg[b * N_ + j0 + jl]));
    }
    __syncthreads();

    #pragma unroll
    for (int it = 0; it < 8; it++) {
        int il = it * 16 + (tid >> 4);
        int jl8 = (tid & 15) * 8;
        const float* zp = z + ((size_t)(b * N_ + i0 + il)) * N_ + j0 + jl8;
        float4 p0 = *(const float4*)zp;
        float4 p1 = *(const float4*)(zp + 4);
        float pv[8] = {p0.x, p0.y, p0.z, p0.w, p1.x, p1.y, p1.z, p1.w};
        f16x8 o;
        float di = Di[il];
        #pragma unroll
        for (int k = 0; k < 8; k++) {
            float v = 0.5f * (sigmoidf_(pv[k]) + (float)mir[(jl8 + k) * 129 + il]);
            if (i0 + il == j0 + jl8 + k) v += 1.0f;
            o[k] = (f16)(v * di * Dj[jl8 + k]);
        }
        *(f16x8*)(nA + ((size_t)(b * N_ + i0 + il)) * N_ + j0 + jl8) = o;
    }
}

// ---------------------------------------------------------------------------
// k_xw1: XW1t[h, node] = sum_k ne[node,k]*w1[k,h] + b1[h]   (f16, transposed)
__global__ __launch_bounds__(256) void k_xw1(const float* __restrict__ ne,
                                             const float* __restrict__ w1,
                                             const float* __restrict__ b1,
                                             f16* __restrict__ XW1t) {
    int h = blockIdx.x;
    int node = threadIdx.x;
    float s = b1[h];
    #pragma unroll 8
    for (int k = 0; k < F_; k++) s += ne[node * F_ + k] * w1[k * H_ + h];
    XW1t[h * N_ + node] = (f16)s;
}

// ---------------------------------------------------------------------------
// k_wt: w{2,3}t[n,k] = w{2,3}[k,n]   (f16 transpose)
__global__ __launch_bounds__(256) void k_wt(const float* __restrict__ w2,
                                            const float* __restrict__ w3,
                                            f16* __restrict__ w2t,
                                            f16* __restrict__ w3t) {
    int which = blockIdx.y;
    const float* src = which ? w3 : w2;
    f16* dst = which ? w3t : w2t;
    int idx = blockIdx.x * 256 + threadIdx.x;
    int k = idx >> 9, n = idx & 511;
    dst[n * H_ + k] = (f16)src[k * H_ + n];
}

// ---------------------------------------------------------------------------
// k_gemm: C(128x128 tile) = A(rows m, K) @ Bt(rows n, K)^T
// MODE 0: Out[b][node][512] = relu(acc)            (GCN aggregation)
// MODE 1: Out[b][n][256]    = acc + bias[n]        (transform, T-layout out)
// MODE 2: g[b][h] += sum_nodes relu(acc)           (fused layer-3 + readout)
template <int KDIM, int MODE>
__global__ __launch_bounds__(256) void k_gemm(const f16* __restrict__ A, long aBatch,
                                              const f16* __restrict__ Bt, long bBatch,
                                              f16* __restrict__ Out,
                                              const float* __restrict__ bias,
                                              float* __restrict__ g) {
    __shared__ f16 As[128 * 32];
    __shared__ f16 Bs[128 * 32];
    const int tid  = threadIdx.x;
    const int lane = tid & 63, wave = tid >> 6;
    const int wm = wave >> 1, wn = wave & 1;
    const int b  = blockIdx.y;
    const int m0 = (blockIdx.x & 1) * 128;
    const int n0 = (blockIdx.x >> 1) * 128;

    const f16* Ab = A + (size_t)b * aBatch;
    const f16* Bb = Bt + (size_t)b * bBatch;

    f32x4 acc[4][4];
    #pragma unroll
    for (int i = 0; i < 4; i++)
        #pragma unroll
        for (int j = 0; j < 4; j++)
            #pragma unroll
            for (int r = 0; r < 4; r++) acc[i][j][r] = 0.0f;

    const int srow = (lane >> 2);
    const int scol = (lane & 3) * 8;

    for (int kk = 0; kk < KDIM; kk += 32) {
        #pragma unroll
        for (int c = 0; c < 2; c++) {
            int chunk = wave * 2 + c;
            int row = chunk * 16 + srow;
            __builtin_amdgcn_global_load_lds(
                (__attribute__((address_space(1))) void*)(Ab + (size_t)(m0 + row) * KDIM + kk + scol),
                (__attribute__((address_space(3))) void*)(&As[chunk * 512]), 16, 0, 0);
            __builtin_amdgcn_global_load_lds(
                (__attribute__((address_space(1))) void*)(Bb + (size_t)(n0 + row) * KDIM + kk + scol),
                (__attribute__((address_space(3))) void*)(&Bs[chunk * 512]), 16, 0, 0);
        }
        __syncthreads();

        f16x8 aF[4], bF[4];
        #pragma unroll
        for (int t = 0; t < 4; t++) {
            aF[t] = *(const f16x8*)&As[(wm * 64 + t * 16 + (lane & 15)) * 32 + (lane >> 4) * 8];
            bF[t] = *(const f16x8*)&Bs[(wn * 64 + t * 16 + (lane & 15)) * 32 + (lane >> 4) * 8];
        }
        #pragma unroll
        for (int mt = 0; mt < 4; mt++)
            #pragma unroll
            for (int nt = 0; nt < 4; nt++)
                acc[mt][nt] = __builtin_amdgcn_mfma_f32_16x16x32_f16(aF[mt], bF[nt], acc[mt][nt], 0, 0, 0);
        __syncthreads();
    }

    const int quad = lane >> 4, ln15 = lane & 15;
    if (MODE == 0) {
        f16* Ob = Out + (size_t)b * (N_ * H_);
        #pragma unroll
        for (int mt = 0; mt < 4; mt++) {
            int node = m0 + wm * 64 + mt * 16 + quad * 4;
            #pragma unroll
            for (int nt = 0; nt < 4; nt++) {
                int h = n0 + wn * 64 + nt * 16 + ln15;
                #pragma unroll
                for (int rr = 0; rr < 4; rr++) {
                    float v = acc[mt][nt][rr];
                    v = v > 0.f ? v : 0.f;
                    Ob[(size_t)(node + rr) * H_ + h] = (f16)v;
                }
            }
        }
    } else if (MODE == 1) {
        f16* Ob = Out + (size_t)b * (H_ * N_);
        #pragma unroll
        for (int nt = 0; nt < 4; nt++) {
            int n = n0 + wn * 64 + nt * 16 + ln15;
            float bv = bias[n];
            #pragma unroll
            for (int mt = 0; mt < 4; mt++) {
                int node = m0 + wm * 64 + mt * 16 + quad * 4;
                f16x4 v;
                #pragma unroll
                for (int rr = 0; rr < 4; rr++) v[rr] = (f16)(acc[mt][nt][rr] + bv);
                *(f16x4*)&Ob[(size_t)n * N_ + node] = v;
            }
        }
    } else {
        // MODE 2: fused relu + node-sum readout into g[b][h]
        #pragma unroll
        for (int nt = 0; nt < 4; nt++) {
            float partial = 0.f;
            #pragma unroll
            for (int mt = 0; mt < 4; mt++)
                #pragma unroll
                for (int rr = 0; rr < 4; rr++) {
                    float v = acc[mt][nt][rr];
                    partial += (v > 0.f ? v : 0.f);
                }
            partial += __shfl_down(partial, 32, 64);
            partial += __shfl_down(partial, 16, 64);
            if (quad == 0) {
                int h = n0 + wn * 64 + nt * 16 + ln15;
                atomicAdd(g + b * H_ + h, partial);
            }
        }
    }
}

// ---------------------------------------------------------------------------
// k_logits: logits[b] = (g[b]/N) @ fcw + fcb.  grid B_ x 256.
__global__ __launch_bounds__(256) void k_logits(const float* __restrict__ g,
                                                const float* __restrict__ fcw,
                                                const float* __restrict__ fcb,
                                                float* __restrict__ out) {
    int b = blockIdx.x, tid = threadIdx.x;
    const float* gb = g + b * H_;
    float g0 = gb[tid], g1 = gb[tid + 256];
    float p0 = g0 * fcw[tid * 2 + 0] + g1 * fcw[(tid + 256) * 2 + 0];
    float p1 = g0 * fcw[tid * 2 + 1] + g1 * fcw[(tid + 256) * 2 + 1];
    for (int off = 32; off; off >>= 1) {
        p0 += __shfl_down(p0, off, 64);
        p1 += __shfl_down(p1, off, 64);
    }
    __shared__ float r0[4], r1[4];
    int lane = tid & 63, w = tid >> 6;
    if (lane == 0) { r0[w] = p0; r1[w] = p1; }
    __syncthreads();
    const float inv = 1.0f / N_;
    if (tid == 0) out[b * 2 + 0] = (r0[0] + r0[1] + r0[2] + r0[3]) * inv + fcb[0];
    if (tid == 1) out[b * 2 + 1] = (r1[0] + r1[1] + r1[2] + r1[3]) * inv + fcb[1];
}

// ---------------------------------------------------------------------------
extern "C" void kernel_launch(void* const* d_in, const int* in_sizes, int n_in,
                              void* d_out, int out_size, void* d_ws, size_t ws_size,
                              hipStream_t stream) {
    const float* z   = (const float*)d_in[0];
    const float* ne  = (const float*)d_in[1];
    const float* w1  = (const float*)d_in[2];
    const float* b1  = (const float*)d_in[3];
    const float* w2  = (const float*)d_in[4];
    const float* b2  = (const float*)d_in[5];
    const float* w3  = (const float*)d_in[6];
    const float* b3  = (const float*)d_in[7];
    const float* fcw = (const float*)d_in[8];
    const float* fcb = (const float*)d_in[9];
    float* out = (float*)d_out;

    char* ws = (char*)d_ws;
    // Layout (bytes). R/Cg alias the head of T (dead before T first written);
    // g aliases the head of Hh (memset issued after last Hh reader launched).
    f16*   T    = (f16*)(ws + 0);            // 67,108,864
    float* R    = (float*)(ws + 0);          //    262,144 (alias T)
    float* Cg   = (float*)(ws + 262144);     //    262,144 (alias T)
    f16*   nA   = (f16*)(ws + 67108864);     // 33,554,432
    f16*   Hh   = (f16*)(ws + 100663296);    // 67,108,864
    float* g    = (float*)(ws + 100663296);  //    524,288 (alias Hh)
    f16*   XW1t = (f16*)(ws + 167772160);    //    262,144
    f16*   w2t  = (f16*)(ws + 168034304);    //    524,288
    f16*   w3t  = (f16*)(ws + 168558592);    //    524,288  (total ~161.2 MB)

    // adjacency preprocessing
    hipMemsetAsync(Cg, 0, N_ * B_ * sizeof(float), stream);
    k_sums  <<<dim3(4, B_), 256, 0, stream>>>(z, R, Cg);
    k_norma2<<<dim3(4, B_), 256, 0, stream>>>(z, R, Cg, nA);
    // weight preprocessing
    k_xw1<<<H_,            256, 0, stream>>>(ne, w1, b1, XW1t);
    k_wt <<<dim3(1024, 2), 256, 0, stream>>>(w2, w3, w2t, w3t);

    // Layer 1: H1 = relu(nA @ XW1)
    k_gemm<256, 0><<<dim3(8, B_), 256, 0, stream>>>(nA, 65536, XW1t, 0, Hh, nullptr, nullptr);
    // T2 = H1 @ w2 + b2  (T-layout out)
    k_gemm<512, 1><<<dim3(8, B_), 256, 0, stream>>>(Hh, 131072, w2t, 0, T, b2, nullptr);
    // Layer 2: H2 = relu(nA @ T2)
    k_gemm<256, 0><<<dim3(8, B_), 256, 0, stream>>>(nA, 65536, T, 131072, Hh, nullptr, nullptr);
    // T3 = H2 @ w3 + b3
    k_gemm<512, 1><<<dim3(8, B_), 256, 0, stream>>>(Hh, 131072, w3t, 0, T, b3, nullptr);
    // g = 0, then Layer 3 fused with readout: g[b][h] = sum_nodes relu(nA @ T3)
    hipMemsetAsync(g, 0, B_ * H_ * sizeof(float), stream);
    k_gemm<256, 2><<<dim3(8, B_), 256, 0, stream>>>(nA, 65536, T, 131072, Hh, nullptr, g);

    // readout
    k_logits<<<B_, 256, 0, stream>>>(g, fcw, fcb, out);
}

// Round 3
// 346.376 us; speedup vs baseline: 1.4837x; 1.2118x over previous
//
#include <hip/hip_runtime.h>
#include <stdint.h>

#define B_ 256
#define N_ 256
#define F_ 64
#define H_ 512

typedef _Float16 f16;
typedef _Float16 f16x8 __attribute__((ext_vector_type(8)));
typedef _Float16 f16x4 __attribute__((ext_vector_type(4)));
typedef float    f32x4 __attribute__((ext_vector_type(4)));

__device__ __forceinline__ float sigmoidf_(float x) {
    return 1.0f / (1.0f + __expf(-x));
}

// ---------------------------------------------------------------------------
// k_sums: one pass over z. S = sigmoid(z) (f16), R[b,i] = row sums,
// Cg[b,j] += col partials (atomic, pre-zeroed). grid (4, B_) x 256.
__global__ __launch_bounds__(256) void k_sums(const float* __restrict__ z,
                                              f16* __restrict__ S,
                                              float* __restrict__ R,
                                              float* __restrict__ Cg) {
    int b = blockIdx.y, c = blockIdx.x;
    int tid = threadIdx.x, lane = tid & 63, w = tid >> 6;
    float colacc[4] = {0.f, 0.f, 0.f, 0.f};
    for (int r = 0; r < 16; r++) {
        int i = c * 64 + w * 16 + r;
        size_t base = ((size_t)(b * N_ + i)) * N_;
        float4 v = *(const float4*)(z + base + lane * 4);
        float s0 = sigmoidf_(v.x), s1 = sigmoidf_(v.y),
              s2 = sigmoidf_(v.z), s3 = sigmoidf_(v.w);
        f16x4 sv = { (f16)s0, (f16)s1, (f16)s2, (f16)s3 };
        *(f16x4*)(S + base + lane * 4) = sv;
        colacc[0] += s0; colacc[1] += s1; colacc[2] += s2; colacc[3] += s3;
        float rs = s0 + s1 + s2 + s3;
        for (int off = 32; off; off >>= 1) rs += __shfl_down(rs, off, 64);
        if (lane == 0) R[b * N_ + i] = rs;
    }
    __shared__ float cbuf[4][N_];
    #pragma unroll
    for (int k = 0; k < 4; k++) cbuf[w][lane * 4 + k] = colacc[k];
    __syncthreads();
    float s = cbuf[0][tid] + cbuf[1][tid] + cbuf[2][tid] + cbuf[3][tid];
    atomicAdd(Cg + b * N_ + tid, s);
}

// ---------------------------------------------------------------------------
// k_norma3: nA[i,j] = (0.5*(S_ij+S_ji)+delta_ij)*Di*Dj, S read exactly once.
// Tile types: 0 -> diag(0,0); 1 -> diag(1,1); 2 -> offdiag pair (0,1)+(1,0).
// grid (3, B_) x 256.
__global__ __launch_bounds__(256) void k_norma3(const f16* __restrict__ S,
                                                const float* __restrict__ R,
                                                const float* __restrict__ Cg,
                                                f16* __restrict__ nA) {
    __shared__ f16 T0[128 * 129];
    __shared__ f16 T1[128 * 129];
    __shared__ float Dv[N_];
    int b = blockIdx.y, t = blockIdx.x;
    int tid = threadIdx.x;
    const f16* Sb = S + (size_t)b * N_ * N_;
    f16* Ab = nA + (size_t)b * N_ * N_;

    Dv[tid] = rsqrtf(1.0f + 1e-6f + 0.5f * (R[b * N_ + tid] + Cg[b * N_ + tid]));

    auto stage = [&](const f16* src, f16* dst) {
        #pragma unroll
        for (int it = 0; it < 8; it++) {
            int u = it * 256 + tid;
            int r = u >> 4, c8 = (u & 15) * 8;
            *(f16x8*)&dst[r * 129 + c8] = *(const f16x8*)&src[(size_t)r * N_ + c8];
        }
    };
    if (t == 0)      stage(Sb, T0);
    else if (t == 1) stage(Sb + 128 * N_ + 128, T0);
    else           { stage(Sb + 128, T0); stage(Sb + (size_t)128 * N_, T1); }
    __syncthreads();

    auto emit = [&](const f16* Dir, const f16* Mir, int i0, int j0) {
        #pragma unroll
        for (int it = 0; it < 8; it++) {
            int il = it * 16 + (tid >> 4), jl8 = (tid & 15) * 8;
            float di = Dv[i0 + il];
            f16x8 d = *(const f16x8*)&Dir[il * 129 + jl8];
            f16x8 o;
            #pragma unroll
            for (int k = 0; k < 8; k++) {
                float v = 0.5f * ((float)d[k] + (float)Mir[(jl8 + k) * 129 + il]);
                if (i0 + il == j0 + jl8 + k) v += 1.0f;
                o[k] = (f16)(v * di * Dv[j0 + jl8 + k]);
            }
            *(f16x8*)&Ab[(size_t)(i0 + il) * N_ + j0 + jl8] = o;
        }
    };
    if (t == 0)      emit(T0, T0, 0, 0);
    else if (t == 1) emit(T0, T0, 128, 128);
    else           { emit(T0, T1, 0, 128); emit(T1, T0, 128, 0); }
}

// ---------------------------------------------------------------------------
// k_xw1: XW1t[h, node] = sum_k ne[node,k]*w1[k,h] + b1[h]   (f16, transposed)
__global__ __launch_bounds__(256) void k_xw1(const float* __restrict__ ne,
                                             const float* __restrict__ w1,
                                             const float* __restrict__ b1,
                                             f16* __restrict__ XW1t) {
    int h = blockIdx.x;
    int node = threadIdx.x;
    float s = b1[h];
    #pragma unroll 8
    for (int k = 0; k < F_; k++) s += ne[node * F_ + k] * w1[k * H_ + h];
    XW1t[h * N_ + node] = (f16)s;
}

// ---------------------------------------------------------------------------
// k_wt: w{2,3}t[n,k] = w{2,3}[k,n]   (f16 transpose)
__global__ __launch_bounds__(256) void k_wt(const float* __restrict__ w2,
                                            const float* __restrict__ w3,
                                            f16* __restrict__ w2t,
                                            f16* __restrict__ w3t) {
    int which = blockIdx.y;
    const float* src = which ? w3 : w2;
    f16* dst = which ? w3t : w2t;
    int idx = blockIdx.x * 256 + threadIdx.x;
    int k = idx >> 9, n = idx & 511;
    dst[n * H_ + k] = (f16)src[k * H_ + n];
}

// ---------------------------------------------------------------------------
// k_gemm: C(128x128 tile) = A(rows m, K) @ Bt(rows n, K)^T, BK=64, XOR-swizzled
// LDS, XCD-grouped tile mapping (flat grid of 2048).
// MODE 0: Out[b][node][512] = relu(acc)
// MODE 1: Out[b][n][256]    = acc + bias[n]
// MODE 2: g[b][h] += sum_nodes relu(acc)
template <int KDIM, int MODE>
__global__ __launch_bounds__(256) void k_gemm(const f16* __restrict__ A, long aBatch,
                                              const f16* __restrict__ Bt, long bBatch,
                                              f16* __restrict__ Out,
                                              const float* __restrict__ bias,
                                              float* __restrict__ g) {
    __shared__ f16 As[128 * 64];
    __shared__ f16 Bs[128 * 64];
    const int tid  = threadIdx.x;
    const int lane = tid & 63, wave = tid >> 6;
    const int wm = wave >> 1, wn = wave & 1;

    // XCD-grouped mapping: each XCD owns whole (b, m-tile) groups; the 4
    // n-tiles sharing an A-tile are consecutive on the same XCD.
    const int lin = blockIdx.x;
    const int xcd = lin & 7, q = lin >> 3;
    const int n_t = q & 3, p = q >> 2;
    const int gp  = xcd * 64 + p;          // 0..511 = (b, m-tile)
    const int b   = gp >> 1, m_t = gp & 1;
    const int m0 = m_t * 128, n0 = n_t * 128;

    const f16* Ab = A + (size_t)b * aBatch;
    const f16* Bb = Bt + (size_t)b * bBatch;

    f32x4 acc[4][4];
    #pragma unroll
    for (int i = 0; i < 4; i++)
        #pragma unroll
        for (int j = 0; j < 4; j++)
            #pragma unroll
            for (int r = 0; r < 4; r++) acc[i][j][r] = 0.0f;

    // loader lane mapping: chunk = 8 rows x 64 f16 (1 KB). Lane -> row lr,
    // swizzled k-chunk kc so LDS slot (= lane) holds (row, kc^row) layout.
    const int lr = lane >> 3;              // row within chunk
    const int kc = (lane & 7) ^ lr;        // global 16B k-chunk to fetch

    for (int kk = 0; kk < KDIM; kk += 64) {
        #pragma unroll
        for (int c = 0; c < 4; c++) {
            int chunk = wave * 4 + c;      // 0..15
            int row = chunk * 8 + lr;      // 0..127
            __builtin_amdgcn_global_load_lds(
                (__attribute__((address_space(1))) void*)(Ab + (size_t)(m0 + row) * KDIM + kk + kc * 8),
                (__attribute__((address_space(3))) void*)(&As[chunk * 512]), 16, 0, 0);
            __builtin_amdgcn_global_load_lds(
                (__attribute__((address_space(1))) void*)(Bb + (size_t)(n0 + row) * KDIM + kk + kc * 8),
                (__attribute__((address_space(3))) void*)(&Bs[chunk * 512]), 16, 0, 0);
        }
        __syncthreads();

        #pragma unroll
        for (int ks = 0; ks < 2; ks++) {
            f16x8 aF[4], bF[4];
            #pragma unroll
            for (int t = 0; t < 4; t++) {
                int rowA = wm * 64 + t * 16 + (lane & 15);
                int rowB = wn * 64 + t * 16 + (lane & 15);
                int rkc  = ks * 4 + (lane >> 4);
                aF[t] = *(const f16x8*)&As[(rowA * 8 + (rkc ^ (rowA & 7))) * 8];
                bF[t] = *(const f16x8*)&Bs[(rowB * 8 + (rkc ^ (rowB & 7))) * 8];
            }
            #pragma unroll
            for (int mt = 0; mt < 4; mt++)
                #pragma unroll
                for (int nt = 0; nt < 4; nt++)
                    acc[mt][nt] = __builtin_amdgcn_mfma_f32_16x16x32_f16(aF[mt], bF[nt], acc[mt][nt], 0, 0, 0);
        }
        __syncthreads();
    }

    const int quad = lane >> 4, ln15 = lane & 15;
    if (MODE == 0) {
        f16* Ob = Out + (size_t)b * (N_ * H_);
        #pragma unroll
        for (int mt = 0; mt < 4; mt++) {
            int node = m0 + wm * 64 + mt * 16 + quad * 4;
            #pragma unroll
            for (int nt = 0; nt < 4; nt++) {
                int h = n0 + wn * 64 + nt * 16 + ln15;
                #pragma unroll
                for (int rr = 0; rr < 4; rr++) {
                    float v = acc[mt][nt][rr];
                    v = v > 0.f ? v : 0.f;
                    Ob[(size_t)(node + rr) * H_ + h] = (f16)v;
                }
            }
        }
    } else if (MODE == 1) {
        f16* Ob = Out + (size_t)b * (H_ * N_);
        #pragma unroll
        for (int nt = 0; nt < 4; nt++) {
            int n = n0 + wn * 64 + nt * 16 + ln15;
            float bv = bias[n];
            #pragma unroll
            for (int mt = 0; mt < 4; mt++) {
                int node = m0 + wm * 64 + mt * 16 + quad * 4;
                f16x4 v;
                #pragma unroll
                for (int rr = 0; rr < 4; rr++) v[rr] = (f16)(acc[mt][nt][rr] + bv);
                *(f16x4*)&Ob[(size_t)n * N_ + node] = v;
            }
        }
    } else {
        #pragma unroll
        for (int nt = 0; nt < 4; nt++) {
            float partial = 0.f;
            #pragma unroll
            for (int mt = 0; mt < 4; mt++)
                #pragma unroll
                for (int rr = 0; rr < 4; rr++) {
                    float v = acc[mt][nt][rr];
                    partial += (v > 0.f ? v : 0.f);
                }
            partial += __shfl_down(partial, 32, 64);
            partial += __shfl_down(partial, 16, 64);
            if (quad == 0) {
                int h = n0 + wn * 64 + nt * 16 + ln15;
                atomicAdd(g + b * H_ + h, partial);
            }
        }
    }
}

// ---------------------------------------------------------------------------
// k_logits: logits[b] = (g[b]/N) @ fcw + fcb.  grid B_ x 256.
__global__ __launch_bounds__(256) void k_logits(const float* __restrict__ g,
                                                const float* __restrict__ fcw,
                                                const float* __restrict__ fcb,
                                                float* __restrict__ out) {
    int b = blockIdx.x, tid = threadIdx.x;
    const float* gb = g + b * H_;
    float g0 = gb[tid], g1 = gb[tid + 256];
    float p0 = g0 * fcw[tid * 2 + 0] + g1 * fcw[(tid + 256) * 2 + 0];
    float p1 = g0 * fcw[tid * 2 + 1] + g1 * fcw[(tid + 256) * 2 + 1];
    for (int off = 32; off; off >>= 1) {
        p0 += __shfl_down(p0, off, 64);
        p1 += __shfl_down(p1, off, 64);
    }
    __shared__ float r0[4], r1[4];
    int lane = tid & 63, w = tid >> 6;
    if (lane == 0) { r0[w] = p0; r1[w] = p1; }
    __syncthreads();
    const float inv = 1.0f / N_;
    if (tid == 0) out[b * 2 + 0] = (r0[0] + r0[1] + r0[2] + r0[3]) * inv + fcb[0];
    if (tid == 1) out[b * 2 + 1] = (r1[0] + r1[1] + r1[2] + r1[3]) * inv + fcb[1];
}

// ---------------------------------------------------------------------------
extern "C" void kernel_launch(void* const* d_in, const int* in_sizes, int n_in,
                              void* d_out, int out_size, void* d_ws, size_t ws_size,
                              hipStream_t stream) {
    const float* z   = (const float*)d_in[0];
    const float* ne  = (const float*)d_in[1];
    const float* w1  = (const float*)d_in[2];
    const float* b1  = (const float*)d_in[3];
    const float* w2  = (const float*)d_in[4];
    const float* b2  = (const float*)d_in[5];
    const float* w3  = (const float*)d_in[6];
    const float* b3  = (const float*)d_in[7];
    const float* fcw = (const float*)d_in[8];
    const float* fcb = (const float*)d_in[9];
    float* out = (float*)d_out;

    char* ws = (char*)d_ws;
    // Layout. R/Cg alias head of T (dead before T first written).
    // S and g alias head of Hh (S dead after k_norma3; g memset after T3 launch).
    f16*   T    = (f16*)(ws + 0);            // 67,108,864
    float* R    = (float*)(ws + 0);          //    262,144 (alias T)
    float* Cg   = (float*)(ws + 262144);     //    262,144 (alias T)
    f16*   nA   = (f16*)(ws + 67108864);     // 33,554,432
    f16*   Hh   = (f16*)(ws + 100663296);    // 67,108,864
    f16*   S    = (f16*)(ws + 100663296);    // 33,554,432 (alias Hh)
    float* g    = (float*)(ws + 100663296);  //    524,288 (alias Hh)
    f16*   XW1t = (f16*)(ws + 167772160);    //    262,144
    f16*   w2t  = (f16*)(ws + 168034304);    //    524,288
    f16*   w3t  = (f16*)(ws + 168558592);    //    524,288

    // adjacency preprocessing
    hipMemsetAsync(Cg, 0, N_ * B_ * sizeof(float), stream);
    k_sums  <<<dim3(4, B_), 256, 0, stream>>>(z, S, R, Cg);
    k_norma3<<<dim3(3, B_), 256, 0, stream>>>(S, R, Cg, nA);
    // weight preprocessing
    k_xw1<<<H_,            256, 0, stream>>>(ne, w1, b1, XW1t);
    k_wt <<<dim3(1024, 2), 256, 0, stream>>>(w2, w3, w2t, w3t);

    // Layer 1: H1 = relu(nA @ XW1)
    k_gemm<256, 0><<<2048, 256, 0, stream>>>(nA, 65536, XW1t, 0, Hh, nullptr, nullptr);
    // T2 = H1 @ w2 + b2  (T-layout out)
    k_gemm<512, 1><<<2048, 256, 0, stream>>>(Hh, 131072, w2t, 0, T, b2, nullptr);
    // Layer 2: H2 = relu(nA @ T2)
    k_gemm<256, 0><<<2048, 256, 0, stream>>>(nA, 65536, T, 131072, Hh, nullptr, nullptr);
    // T3 = H2 @ w3 + b3
    k_gemm<512, 1><<<2048, 256, 0, stream>>>(Hh, 131072, w3t, 0, T, b3, nullptr);
    // Layer 3 fused with readout: g[b][h] = sum_nodes relu(nA @ T3)
    hipMemsetAsync(g, 0, B_ * H_ * sizeof(float), stream);
    k_gemm<256, 2><<<2048, 256, 0, stream>>>(nA, 65536, T, 131072, Hh, nullptr, g);

    // readout
    k_logits<<<B_, 256, 0, stream>>>(g, fcw, fcb, out);
}